// Round 3
// baseline (5502.541 us; speedup 1.0000x reference)
//
#include <hip/hip_runtime.h>
#include <stdint.h>

#define T_LEN 512
#define NB 64
#define STOPID 30

typedef unsigned short u16;
typedef unsigned int u32;
typedef short bf8 __attribute__((ext_vector_type(8)));
typedef float f32x4 __attribute__((ext_vector_type(4)));

__device__ __forceinline__ float bf2f(u16 v){ return __uint_as_float(((u32)v) << 16); }
__device__ __forceinline__ u16 f2bf(float f){
  u32 u = __float_as_uint(f);
  return (u16)((u + 0x7FFFu + ((u >> 16) & 1u)) >> 16);
}
__device__ __forceinline__ float sigm(float x){ return 1.0f/(1.0f + __expf(-x)); }
__device__ __forceinline__ float tanhfast(float x){ return 1.0f - 2.0f/(1.0f + __expf(2.0f*x)); }

// ---------------- K0: fp32 -> bf16 weight conversion (Whh + Wih, both dirs) ----------------
extern "C" __global__ __launch_bounds__(256) void k0_cvt(
    const float* __restrict__ whf, const float* __restrict__ whb,
    const float* __restrict__ wif, const float* __restrict__ wib,
    u16* __restrict__ whh_bf, u16* __restrict__ wih_bf)
{
  int i = blockIdx.x * 256 + threadIdx.x;   // grid 1024 -> 262144
  whh_bf[i]          = f2bf(whf[i]);
  whh_bf[262144 + i] = f2bf(whb[i]);
  wih_bf[i]          = f2bf(wif[i]);
  wih_bf[262144 + i] = f2bf(wib[i]);
}

// ---------------- K_init: zero h_init + barrier flags; compute lengths ----------------
extern "C" __global__ __launch_bounds__(256) void k_init(
    const int* __restrict__ mask, u32* __restrict__ h_init_u32,
    u32* __restrict__ cnt, int* __restrict__ lenv)
{
  int bid = blockIdx.x, tid = threadIdx.x;
  if (bid < 32) {
    h_init_u32[bid*256 + tid] = 0u;           // 8192 u32 = 32KB zeros (64x256 bf16 zeros)
  } else if (bid == 32) {
    cnt[tid] = 0u; cnt[256+tid] = 0u; cnt[512+tid] = 0u; cnt[768+tid] = 0u;
  } else {
    if (tid < 64) lenv[tid] = 0;
    __syncthreads();
    int r = tid >> 2, p = tid & 3;
    int s = 0;
    for (int k = 0; k < 128; ++k) s += mask[r*T_LEN + p*128 + k];
    atomicAdd(&lenv[r], s);
  }
}

// ---------------- KG: gather emb[inp] and convert to bf16, layout [t*64+b][256] ----------------
extern "C" __global__ __launch_bounds__(256) void kg_emb(
    const int* __restrict__ inp, const float* __restrict__ emb, u16* __restrict__ xemb)
{
  int r = blockIdx.x*2 + (threadIdx.x >> 7);    // 0..32767
  int col = (threadIdx.x & 127) * 2;
  int b = r & 63, t = r >> 6;
  int tok = inp[b*T_LEN + t];
  float2 v = *(const float2*)(emb + (size_t)tok*256 + col);
  u32 pk = ((u32)f2bf(v.x)) | (((u32)f2bf(v.y)) << 16);
  *(u32*)(xemb + (size_t)r*256 + col) = pk;
}

// ---------------- K1: xW[dir][t][gate][row] = bf16( xemb @ Wih^T + b ) via MFMA ----------------
extern "C" __global__ __launch_bounds__(256) void k1_proj(
    const u16* __restrict__ xemb, const u16* __restrict__ wih,
    const float* __restrict__ b_f, const float* __restrict__ b_b,
    u16* __restrict__ xW)
{
  int t  = blockIdx.x;
  int gb = blockIdx.y;              // 0..31
  int dir  = gb >> 4;
  int nblk = gb & 15;               // 64-gate block within dir
  int w    = threadIdx.x >> 6;      // wave id = M-tile (rows 16w..16w+16)
  int lane = threadIdx.x & 63;
  int lr = lane & 15, q = lane >> 4;

  bf8 af[8];
  #pragma unroll
  for (int kt = 0; kt < 8; ++kt)
    af[kt] = *(const bf8*)(xemb + ((size_t)t*64 + w*16 + lr)*256 + kt*32 + q*8);

  const u16* wbase = wih + (size_t)dir*262144 + (size_t)nblk*64*256;
  f32x4 acc[4];
  #pragma unroll
  for (int n = 0; n < 4; ++n) { acc[n][0]=0.f; acc[n][1]=0.f; acc[n][2]=0.f; acc[n][3]=0.f; }
  #pragma unroll
  for (int n = 0; n < 4; ++n) {
    #pragma unroll
    for (int kt = 0; kt < 8; ++kt) {
      bf8 b = *(const bf8*)(wbase + (size_t)(n*16 + lr)*256 + kt*32 + q*8);
      acc[n] = __builtin_amdgcn_mfma_f32_16x16x32_bf16(af[kt], b, acc[n], 0, 0, 0);
    }
  }

  const float* bias = dir ? b_b : b_f;
  u16* xp = xW + ((size_t)(dir*T_LEN + t)*1024 + nblk*64)*64;
  #pragma unroll
  for (int n = 0; n < 4; ++n) {
    float bv = bias[nblk*64 + n*16 + lr];
    ushort4 st;
    st.x = f2bf(acc[n][0] + bv);
    st.y = f2bf(acc[n][1] + bv);
    st.z = f2bf(acc[n][2] + bv);
    st.w = f2bf(acc[n][3] + bv);
    *(ushort4*)(xp + (size_t)(n*16 + lr)*64 + w*16 + q*4) = st;
  }
}

// ---------------- K2: LSTM recurrence, 32 waves (16 blocks x 2) per direction ----------------
// Wave w (0..31): rows [32*(w>>4),+32), channels [16*(w&15),+16), all 4 gates. Whh fragments
// register-resident all 512 steps (launch_bounds(128,1) -> 512 VGPR budget, no spill).
// Barrier: per-block flag store + block-0 aggregator + single "go" word, relaxed spins +
// explicit agent fences (no contended RMW).
extern "C" __global__ __launch_bounds__(128, 1) void k2_lstm(
    const u16* __restrict__ whh, const u16* __restrict__ xW,
    const int* __restrict__ lenv, const u16* __restrict__ h_init,
    u16* __restrict__ h_out, u32* __restrict__ cnt)
{
  int blk = blockIdx.x;             // 0..31
  int dir = blk >> 4;
  int bb  = blk & 15;
  int wv  = threadIdx.x >> 6;
  int lane = threadIdx.x & 63;
  int w  = bb*2 + wv;               // 0..31
  int rg = w >> 4;                  // row group (32 rows)
  int cs = w & 15;                  // chan slice (16 chans)
  int lr = lane & 15, q = lane >> 4;
  int r0 = rg*32;
  int c0 = cs*16;

  // Whh B-fragments: 4 gates x 8 K-steps, register-resident (128 VGPRs)
  bf8 bw[4][8];
  const u16* wbase = whh + (size_t)dir*262144;
  #pragma unroll
  for (int g = 0; g < 4; ++g)
    #pragma unroll
    for (int kt = 0; kt < 8; ++kt)
      bw[g][kt] = *(const bf8*)(wbase + (size_t)(g*256 + c0 + lr)*256 + kt*32 + q*8);

  float cst[2][4] = {{0.f,0.f,0.f,0.f},{0.f,0.f,0.f,0.f}};
  float hst[2][4] = {{0.f,0.f,0.f,0.f},{0.f,0.f,0.f,0.f}};
  int4 ln[2];
  ln[0] = *(const int4*)(lenv + r0 + q*4);
  ln[1] = *(const int4*)(lenv + r0 + 16 + q*4);

  u32* flags = cnt + dir*256;       // block bb's flag at flags[bb*16] (64B spacing)
  u32* go    = cnt + 512 + dir*16;

  int t = dir ? (T_LEN-1) : 0;
  ushort4 xv[2][4];
  {
    const u16* xp = xW + (size_t)(dir*T_LEN + t)*1024*64;
    #pragma unroll
    for (int rt = 0; rt < 2; ++rt)
      #pragma unroll
      for (int g = 0; g < 4; ++g)
        xv[rt][g] = *(const ushort4*)(xp + (size_t)(g*256 + c0 + lr)*64 + r0 + rt*16 + q*4);
  }
  const u16* hprev = h_init;

  for (int s = 0; s < T_LEN; ++s) {
    bf8 af[2][8];
    #pragma unroll
    for (int rt = 0; rt < 2; ++rt)
      #pragma unroll
      for (int kt = 0; kt < 8; ++kt)
        af[rt][kt] = *(const bf8*)(hprev + (size_t)(r0 + rt*16 + lr)*256 + kt*32 + q*8);

    f32x4 acc[2][4];
    #pragma unroll
    for (int rt = 0; rt < 2; ++rt)
      #pragma unroll
      for (int g = 0; g < 4; ++g) { acc[rt][g][0]=0.f; acc[rt][g][1]=0.f; acc[rt][g][2]=0.f; acc[rt][g][3]=0.f; }
    #pragma unroll
    for (int kt = 0; kt < 8; ++kt) {   // 8 independent acc chains per stage
      #pragma unroll
      for (int rt = 0; rt < 2; ++rt)
        #pragma unroll
        for (int g = 0; g < 4; ++g)
          acc[rt][g] = __builtin_amdgcn_mfma_f32_16x16x32_bf16(af[rt][kt], bw[g][kt], acc[rt][g], 0, 0, 0);
    }

    u16* hop = h_out + (size_t)(dir*T_LEN + t)*NB*256;
    #pragma unroll
    for (int rt = 0; rt < 2; ++rt) {
      #pragma unroll
      for (int J = 0; J < 4; ++J) {
        float ip = acc[rt][0][J] + bf2f(((const u16*)&xv[rt][0])[J]);
        float fp = acc[rt][1][J] + bf2f(((const u16*)&xv[rt][1])[J]);
        float gp = acc[rt][2][J] + bf2f(((const u16*)&xv[rt][2])[J]);
        float op = acc[rt][3][J] + bf2f(((const u16*)&xv[rt][3])[J]);
        float cn = sigm(fp)*cst[rt][J] + sigm(ip)*tanhfast(gp);
        float hn = sigm(op)*tanhfast(cn);
        int lnj = ((const int*)&ln[rt])[J];
        bool mk = (t < lnj);
        cst[rt][J] = mk ? cn : cst[rt][J];
        hst[rt][J] = mk ? hn : hst[rt][J];
        hop[(size_t)(r0 + rt*16 + q*4 + J)*256 + c0 + lr] = f2bf(hst[rt][J]);
      }
    }

    if (s < T_LEN-1) {
      __builtin_amdgcn_fence(__ATOMIC_RELEASE, "agent");   // drain my h stores to agent scope
      __syncthreads();                                     // all waves of block arrived
      if (threadIdx.x == 0)
        __hip_atomic_store(&flags[bb*16], (u32)(s+1), __ATOMIC_RELAXED, __HIP_MEMORY_SCOPE_AGENT);
      if (bb == 0 && threadIdx.x == 0) {                   // aggregator
        for (int i = 0; i < 16; ++i)
          while (__hip_atomic_load(&flags[i*16], __ATOMIC_RELAXED, __HIP_MEMORY_SCOPE_AGENT) < (u32)(s+1)) {}
        __builtin_amdgcn_fence(__ATOMIC_ACQ_REL, "agent");
        __hip_atomic_store(go, (u32)(s+1), __ATOMIC_RELAXED, __HIP_MEMORY_SCOPE_AGENT);
      }
      int tn = dir ? (T_LEN-2 - s) : (s + 1);
      {  // prefetch next xW while waiting
        const u16* xp = xW + (size_t)(dir*T_LEN + tn)*1024*64;
        #pragma unroll
        for (int rt = 0; rt < 2; ++rt)
          #pragma unroll
          for (int g = 0; g < 4; ++g)
            xv[rt][g] = *(const ushort4*)(xp + (size_t)(g*256 + c0 + lr)*64 + r0 + rt*16 + q*4);
      }
      if (threadIdx.x == 0) {
        while (__hip_atomic_load(go, __ATOMIC_RELAXED, __HIP_MEMORY_SCOPE_AGENT) < (u32)(s+1)) {}
      }
      __syncthreads();
      __builtin_amdgcn_fence(__ATOMIC_ACQUIRE, "agent");
      hprev = hop;
      t = tn;
    }
  }
}

// ---------------- K3: emissions em[t*64+b][32] = [h_f|h_b] @ W_tag^T + b_tag (fp32 out) ----------------
extern "C" __global__ __launch_bounds__(256, 2) void k3_emit(
    const u16* __restrict__ h_out, const float* __restrict__ W_tag,
    const float* __restrict__ b_tag, float* __restrict__ em)
{
  int wv = threadIdx.x >> 6, lane = threadIdx.x & 63;
  int lr = lane & 15, q = lane >> 4;
  size_t r0 = ((size_t)blockIdx.x*4 + wv) * 16;   // grid 1024 -> 4096 row tiles

  bf8 a[16];
  #pragma unroll
  for (int kt = 0; kt < 16; ++kt) {
    const u16* hp = h_out + (size_t)(kt>>3)*T_LEN*NB*256 + (r0 + lr)*256 + (kt&7)*32 + q*8;
    a[kt] = *(const bf8*)hp;
  }
  f32x4 acc[2];
  acc[0][0]=0.f;acc[0][1]=0.f;acc[0][2]=0.f;acc[0][3]=0.f; acc[1]=acc[0];
  #pragma unroll
  for (int n = 0; n < 2; ++n) {
    #pragma unroll
    for (int kt = 0; kt < 16; ++kt) {
      const float* wr = W_tag + (size_t)(n*16 + lr)*512 + kt*32 + q*8;
      bf8 bfr;
      #pragma unroll
      for (int e = 0; e < 8; ++e) bfr[e] = (short)f2bf(wr[e]);
      acc[n] = __builtin_amdgcn_mfma_f32_16x16x32_bf16(a[kt], bfr, acc[n], 0, 0, 0);
    }
  }
  #pragma unroll
  for (int n = 0; n < 2; ++n) {
    float bt = b_tag[n*16 + lr];
    #pragma unroll
    for (int J = 0; J < 4; ++J)
      em[(r0 + q*4 + J)*32 + n*16 + lr] = acc[n][J] + bt;
  }
}

// ---------------- K5: CRF forward scan + gold score; half-wave (32 lanes) per batch row ----------------
extern "C" __global__ __launch_bounds__(64) void k5_crf(
    const int* __restrict__ gold, const int* __restrict__ lenv,
    const float* __restrict__ em, const float* __restrict__ trans,
    float* __restrict__ out)
{
  __shared__ float trans_s[32][33];
  int tid = threadIdx.x;
  for (int i = tid; i < 1024; i += 64) trans_s[i>>5][i&31] = trans[i];
  __syncthreads();

  int half = tid >> 5;
  int j = tid & 31;                 // tag
  int b = blockIdx.x*2 + half;      // grid 32 -> b 0..63
  int len = lenv[b];
  float score = (j == STOPID) ? 0.f : -10000.f;
  float gscore = 0.f;
  int g_cur = gold[b*T_LEN];

  for (int t = 0; t < len; ++t) {
    float e = em[((size_t)t*64 + b)*32 + j];
    float m = -3.0e38f;
    #pragma unroll
    for (int p = 0; p < 32; ++p) {
      float sp = __shfl(score, p, 32);
      m = fmaxf(m, sp + trans_s[j][p]);
    }
    float se = 0.f;
    #pragma unroll
    for (int p = 0; p < 32; ++p) {
      float sp = __shfl(score, p, 32);
      se += __expf(sp + trans_s[j][p] - m);
    }
    score = e + m + __logf(se);
    if (t + 1 < T_LEN) {
      int g_next = gold[b*T_LEN + t + 1];
      float emg = __shfl(e, g_next, 32);
      gscore += emg + trans_s[g_next][g_cur];
      g_cur = g_next;
    }
  }
  float v = score + trans_s[STOPID][j];
  float m = v;
  #pragma unroll
  for (int off = 16; off; off >>= 1) m = fmaxf(m, __shfl_xor(m, off, 32));
  float se = __expf(v - m);
  #pragma unroll
  for (int off = 16; off; off >>= 1) se += __shfl_xor(se, off, 32);
  float Z = m + __logf(se);
  if (j == 0) {
    int g_last = gold[b*T_LEN + len - 1];
    out[b] = Z - (gscore + trans_s[STOPID][g_last]);
  }
}

extern "C" void kernel_launch(void* const* d_in, const int* in_sizes, int n_in,
                              void* d_out, int out_size, void* d_ws, size_t ws_size,
                              hipStream_t stream)
{
  const int*   inp   = (const int*)  d_in[0];
  const int*   gold  = (const int*)  d_in[1];
  const int*   mask  = (const int*)  d_in[2];
  const float* emb   = (const float*)d_in[3];
  const float* Wih_f = (const float*)d_in[4];
  const float* Whh_f = (const float*)d_in[5];
  const float* b_f   = (const float*)d_in[6];
  const float* Wih_b = (const float*)d_in[7];
  const float* Whh_b = (const float*)d_in[8];
  const float* b_b   = (const float*)d_in[9];
  const float* W_tag = (const float*)d_in[10];
  const float* b_tag = (const float*)d_in[11];
  const float* trans = (const float*)d_in[12];
  float* out = (float*)d_out;

  char* ws = (char*)d_ws;
  u16* whh_bf = (u16*)(ws + 0);                 // 1 MiB
  u16* wih_bf = (u16*)(ws + 1048576);           // 1 MiB
  u16* xW     = (u16*)(ws + 2097152);           // 128 MiB [dir][t][gate][row]   (lifetime: k1..k2)
  float* em   = (float*)(ws + 2097152);         // 8 MiB OVERLAY on xW           (lifetime: k3..k5)
  u16* h_outp = (u16*)(ws + 136314880);         // 32 MiB  [dir][t][row][256]    (lifetime: k2..k3)
  u16* xemb   = (u16*)(ws + 136314880);         // 16 MiB OVERLAY on h_out       (lifetime: kg..k1)
  u16* h_init = (u16*)(ws + 169869312);         // 32 KiB zeros
  u32* cntp   = (u32*)(ws + 169902080);         // 4 KiB barrier flags/go
  int* lenv   = (int*)(ws + 169906176);         // 256 B

  hipLaunchKernelGGL(k0_cvt,  dim3(1024),     dim3(256), 0, stream,
                     Whh_f, Whh_b, Wih_f, Wih_b, whh_bf, wih_bf);
  hipLaunchKernelGGL(k_init,  dim3(34),       dim3(256), 0, stream,
                     mask, (u32*)h_init, cntp, lenv);
  hipLaunchKernelGGL(kg_emb,  dim3(16384),    dim3(256), 0, stream, inp, emb, xemb);
  hipLaunchKernelGGL(k1_proj, dim3(512, 32),  dim3(256), 0, stream,
                     xemb, wih_bf, b_f, b_b, xW);
  hipLaunchKernelGGL(k2_lstm, dim3(32),       dim3(128), 0, stream,
                     whh_bf, xW, lenv, h_init, h_outp, cntp);
  hipLaunchKernelGGL(k3_emit, dim3(1024),     dim3(256), 0, stream,
                     h_outp, W_tag, b_tag, em);
  hipLaunchKernelGGL(k5_crf,  dim3(32),       dim3(64),  0, stream,
                     gold, lenv, em, trans, out);
}

// Round 4
// 4760.089 us; speedup vs baseline: 1.1560x; 1.1560x over previous
//
#include <hip/hip_runtime.h>
#include <stdint.h>

#define T_LEN 512
#define NB 64
#define STOPID 30

typedef unsigned short u16;
typedef unsigned int u32;
typedef short bf8 __attribute__((ext_vector_type(8)));
typedef float f32x4 __attribute__((ext_vector_type(4)));

__device__ __forceinline__ float bf2f(u16 v){ return __uint_as_float(((u32)v) << 16); }
__device__ __forceinline__ u16 f2bf(float f){
  u32 u = __float_as_uint(f);
  return (u16)((u + 0x7FFFu + ((u >> 16) & 1u)) >> 16);
}
__device__ __forceinline__ float sigm(float x){ return 1.0f/(1.0f + __expf(-x)); }
__device__ __forceinline__ float tanhfast(float x){ return 1.0f - 2.0f/(1.0f + __expf(2.0f*x)); }

// ---------------- K0: fp32 -> bf16 weight conversion (Whh + Wih, both dirs) ----------------
extern "C" __global__ __launch_bounds__(256) void k0_cvt(
    const float* __restrict__ whf, const float* __restrict__ whb,
    const float* __restrict__ wif, const float* __restrict__ wib,
    u16* __restrict__ whh_bf, u16* __restrict__ wih_bf)
{
  int i = blockIdx.x * 256 + threadIdx.x;   // grid 1024 -> 262144
  whh_bf[i]          = f2bf(whf[i]);
  whh_bf[262144 + i] = f2bf(whb[i]);
  wih_bf[i]          = f2bf(wif[i]);
  wih_bf[262144 + i] = f2bf(wib[i]);
}

// ---------------- K_init: zero h_init + barrier flags; compute lengths ----------------
extern "C" __global__ __launch_bounds__(256) void k_init(
    const int* __restrict__ mask, u32* __restrict__ h_init_u32,
    u32* __restrict__ cnt, int* __restrict__ lenv)
{
  int bid = blockIdx.x, tid = threadIdx.x;
  if (bid < 32) {
    h_init_u32[bid*256 + tid] = 0u;           // 8192 u32 = 32KB zeros (64x256 bf16 zeros)
  } else if (bid == 32) {
    cnt[tid] = 0u; cnt[256+tid] = 0u; cnt[512+tid] = 0u; cnt[768+tid] = 0u;
  } else {
    if (tid < 64) lenv[tid] = 0;
    __syncthreads();
    int r = tid >> 2, p = tid & 3;
    int s = 0;
    for (int k = 0; k < 128; ++k) s += mask[r*T_LEN + p*128 + k];
    atomicAdd(&lenv[r], s);
  }
}

// ---------------- KG: gather emb[inp] and convert to bf16, layout [t*64+b][256] ----------------
extern "C" __global__ __launch_bounds__(256) void kg_emb(
    const int* __restrict__ inp, const float* __restrict__ emb, u16* __restrict__ xemb)
{
  int r = blockIdx.x*2 + (threadIdx.x >> 7);    // 0..32767
  int col = (threadIdx.x & 127) * 2;
  int b = r & 63, t = r >> 6;
  int tok = inp[b*T_LEN + t];
  float2 v = *(const float2*)(emb + (size_t)tok*256 + col);
  u32 pk = ((u32)f2bf(v.x)) | (((u32)f2bf(v.y)) << 16);
  *(u32*)(xemb + (size_t)r*256 + col) = pk;
}

// ---------------- K1: xW[dir][t][gate][row] = bf16( xemb @ Wih^T + b ) via MFMA ----------------
extern "C" __global__ __launch_bounds__(256) void k1_proj(
    const u16* __restrict__ xemb, const u16* __restrict__ wih,
    const float* __restrict__ b_f, const float* __restrict__ b_b,
    u16* __restrict__ xW)
{
  int t  = blockIdx.x;
  int gb = blockIdx.y;              // 0..31
  int dir  = gb >> 4;
  int nblk = gb & 15;               // 64-gate block within dir
  int w    = threadIdx.x >> 6;      // wave id = M-tile (rows 16w..16w+16)
  int lane = threadIdx.x & 63;
  int lr = lane & 15, q = lane >> 4;

  bf8 af[8];
  #pragma unroll
  for (int kt = 0; kt < 8; ++kt)
    af[kt] = *(const bf8*)(xemb + ((size_t)t*64 + w*16 + lr)*256 + kt*32 + q*8);

  const u16* wbase = wih + (size_t)dir*262144 + (size_t)nblk*64*256;
  f32x4 acc[4];
  #pragma unroll
  for (int n = 0; n < 4; ++n) { acc[n][0]=0.f; acc[n][1]=0.f; acc[n][2]=0.f; acc[n][3]=0.f; }
  #pragma unroll
  for (int n = 0; n < 4; ++n) {
    #pragma unroll
    for (int kt = 0; kt < 8; ++kt) {
      bf8 b = *(const bf8*)(wbase + (size_t)(n*16 + lr)*256 + kt*32 + q*8);
      acc[n] = __builtin_amdgcn_mfma_f32_16x16x32_bf16(af[kt], b, acc[n], 0, 0, 0);
    }
  }

  const float* bias = dir ? b_b : b_f;
  u16* xp = xW + ((size_t)(dir*T_LEN + t)*1024 + nblk*64)*64;
  #pragma unroll
  for (int n = 0; n < 4; ++n) {
    float bv = bias[nblk*64 + n*16 + lr];
    ushort4 st;
    st.x = f2bf(acc[n][0] + bv);
    st.y = f2bf(acc[n][1] + bv);
    st.z = f2bf(acc[n][2] + bv);
    st.w = f2bf(acc[n][3] + bv);
    *(ushort4*)(xp + (size_t)(n*16 + lr)*64 + w*16 + q*4) = st;
  }
}

// ---------------- K2: LSTM recurrence ----------------
// Sync domain = (dir, 32-row group): 16 waves over 4 blocks x 256 thr. Wave owns 16 chans x
// 4 gates (64 gate-rows), K=256: weight frags = 128 VGPRs, pinned register-resident by null
// inline asm (compiler cannot rematerialize asm-defined values from memory). Per step:
// 64 MFMA + epilogue + flat 4-flag single-cacheline barrier (release fence + relaxed flag
// store; wave-0 lanes 0-3 poll all flags in one coalesced load, s_sleep backoff).
extern "C" __global__ __launch_bounds__(256, 1) void k2_lstm(
    const u16* __restrict__ whh, const u16* __restrict__ xW,
    const int* __restrict__ lenv, const u16* __restrict__ h_init,
    u16* __restrict__ h_out, u32* __restrict__ cnt)
{
  int blk = blockIdx.x;             // 0..15
  int dir = blk >> 3;
  int rg  = (blk >> 2) & 1;
  int bb  = blk & 3;
  int wv  = threadIdx.x >> 6;
  int lane = threadIdx.x & 63;
  int w  = bb*4 + wv;               // 0..15: chan slice
  int c0 = w*16;
  int lr = lane & 15, q = lane >> 4;
  int r0 = rg*32;

  // Whh B-fragments: 4 gates x 8 K-steps (128 VGPRs), pinned below
  bf8 bw[4][8];
  const u16* wbase = whh + (size_t)dir*262144;
  #pragma unroll
  for (int g = 0; g < 4; ++g)
    #pragma unroll
    for (int kt = 0; kt < 8; ++kt)
      bw[g][kt] = *(const bf8*)(wbase + (size_t)(g*256 + c0 + lr)*256 + kt*32 + q*8);
  #pragma unroll
  for (int g = 0; g < 4; ++g) {
    asm volatile("" : "+v"(bw[g][0]), "+v"(bw[g][1]), "+v"(bw[g][2]), "+v"(bw[g][3]));
    asm volatile("" : "+v"(bw[g][4]), "+v"(bw[g][5]), "+v"(bw[g][6]), "+v"(bw[g][7]));
  }

  float cst[2][4] = {{0.f,0.f,0.f,0.f},{0.f,0.f,0.f,0.f}};
  float hst[2][4] = {{0.f,0.f,0.f,0.f},{0.f,0.f,0.f,0.f}};
  int4 ln[2];
  ln[0] = *(const int4*)(lenv + r0 + q*4);
  ln[1] = *(const int4*)(lenv + r0 + 16 + q*4);

  u32* flg = cnt + (size_t)(dir*2 + rg)*32;   // 4 dwords used, domains 128B apart

  int t = dir ? (T_LEN-1) : 0;
  ushort4 xv[2][4];
  {
    const u16* xp = xW + (size_t)(dir*T_LEN + t)*1024*64;
    #pragma unroll
    for (int mt = 0; mt < 2; ++mt)
      #pragma unroll
      for (int g = 0; g < 4; ++g)
        xv[mt][g] = *(const ushort4*)(xp + (size_t)(g*256 + c0 + lr)*64 + r0 + mt*16 + q*4);
  }
  const u16* hprev = h_init;

  for (int s = 0; s < T_LEN; ++s) {
    bf8 af[2][8];
    #pragma unroll
    for (int mt = 0; mt < 2; ++mt)
      #pragma unroll
      for (int kt = 0; kt < 8; ++kt)
        af[mt][kt] = *(const bf8*)(hprev + (size_t)(r0 + mt*16 + lr)*256 + kt*32 + q*8);

    f32x4 acc[2][4];
    #pragma unroll
    for (int mt = 0; mt < 2; ++mt)
      #pragma unroll
      for (int g = 0; g < 4; ++g) { acc[mt][g][0]=0.f; acc[mt][g][1]=0.f; acc[mt][g][2]=0.f; acc[mt][g][3]=0.f; }
    #pragma unroll
    for (int kt = 0; kt < 8; ++kt) {   // 8 independent chains
      #pragma unroll
      for (int mt = 0; mt < 2; ++mt)
        #pragma unroll
        for (int g = 0; g < 4; ++g)
          acc[mt][g] = __builtin_amdgcn_mfma_f32_16x16x32_bf16(af[mt][kt], bw[g][kt], acc[mt][g], 0, 0, 0);
    }

    u16* hop = h_out + (size_t)(dir*T_LEN + t)*NB*256;
    #pragma unroll
    for (int mt = 0; mt < 2; ++mt) {
      #pragma unroll
      for (int J = 0; J < 4; ++J) {
        float ip = acc[mt][0][J] + bf2f(((const u16*)&xv[mt][0])[J]);
        float fp = acc[mt][1][J] + bf2f(((const u16*)&xv[mt][1])[J]);
        float gp = acc[mt][2][J] + bf2f(((const u16*)&xv[mt][2])[J]);
        float op = acc[mt][3][J] + bf2f(((const u16*)&xv[mt][3])[J]);
        float cn = sigm(fp)*cst[mt][J] + sigm(ip)*tanhfast(gp);
        float hn = sigm(op)*tanhfast(cn);
        int lnj = ((const int*)&ln[mt])[J];
        bool mk = (t < lnj);
        cst[mt][J] = mk ? cn : cst[mt][J];
        hst[mt][J] = mk ? hn : hst[mt][J];
        __builtin_nontemporal_store(f2bf(hst[mt][J]),
            &hop[(size_t)(r0 + mt*16 + q*4 + J)*256 + c0 + lr]);
      }
    }

    if (s < T_LEN-1) {
      __builtin_amdgcn_fence(__ATOMIC_RELEASE, "agent");   // publish my h stores
      __syncthreads();                                     // all 4 waves of block done
      if (threadIdx.x == 0)
        __hip_atomic_store(&flg[bb], (u32)(s+1), __ATOMIC_RELAXED, __HIP_MEMORY_SCOPE_AGENT);
      int tn = dir ? (T_LEN-2 - s) : (s + 1);
      {  // prefetch next xW while waiting
        const u16* xp = xW + (size_t)(dir*T_LEN + tn)*1024*64;
        #pragma unroll
        for (int mt = 0; mt < 2; ++mt)
          #pragma unroll
          for (int g = 0; g < 4; ++g)
            xv[mt][g] = *(const ushort4*)(xp + (size_t)(g*256 + c0 + lr)*64 + r0 + mt*16 + q*4);
      }
      if (wv == 0) {                                       // flat poll: lanes 0-3, one line
        u32 target = (u32)(s+1);
        for (;;) {
          u32 f = 0xFFFFFFFFu;
          if (lane < 4)
            f = __hip_atomic_load(&flg[lane], __ATOMIC_RELAXED, __HIP_MEMORY_SCOPE_AGENT);
          if (__all((int)(f >= target))) break;
          __builtin_amdgcn_s_sleep(2);
        }
      }
      __syncthreads();
      __builtin_amdgcn_fence(__ATOMIC_ACQUIRE, "agent");   // invalidate stale cached h
      hprev = hop;
      t = tn;
    }
  }
}

// ---------------- K3: emissions em[t*64+b][32] = [h_f|h_b] @ W_tag^T + b_tag (fp32 out) ----------------
extern "C" __global__ __launch_bounds__(256, 2) void k3_emit(
    const u16* __restrict__ h_out, const float* __restrict__ W_tag,
    const float* __restrict__ b_tag, float* __restrict__ em)
{
  int wv = threadIdx.x >> 6, lane = threadIdx.x & 63;
  int lr = lane & 15, q = lane >> 4;
  size_t r0 = ((size_t)blockIdx.x*4 + wv) * 16;   // grid 1024 -> 4096 row tiles

  bf8 a[16];
  #pragma unroll
  for (int kt = 0; kt < 16; ++kt) {
    const u16* hp = h_out + (size_t)(kt>>3)*T_LEN*NB*256 + (r0 + lr)*256 + (kt&7)*32 + q*8;
    a[kt] = *(const bf8*)hp;
  }
  f32x4 acc[2];
  acc[0][0]=0.f;acc[0][1]=0.f;acc[0][2]=0.f;acc[0][3]=0.f; acc[1]=acc[0];
  #pragma unroll
  for (int n = 0; n < 2; ++n) {
    #pragma unroll
    for (int kt = 0; kt < 16; ++kt) {
      const float* wr = W_tag + (size_t)(n*16 + lr)*512 + kt*32 + q*8;
      bf8 bfr;
      #pragma unroll
      for (int e = 0; e < 8; ++e) bfr[e] = (short)f2bf(wr[e]);
      acc[n] = __builtin_amdgcn_mfma_f32_16x16x32_bf16(a[kt], bfr, acc[n], 0, 0, 0);
    }
  }
  #pragma unroll
  for (int n = 0; n < 2; ++n) {
    float bt = b_tag[n*16 + lr];
    #pragma unroll
    for (int J = 0; J < 4; ++J)
      em[(r0 + q*4 + J)*32 + n*16 + lr] = acc[n][J] + bt;
  }
}

// ---------------- K5: CRF forward scan + gold score; half-wave (32 lanes) per batch row ----------------
extern "C" __global__ __launch_bounds__(64) void k5_crf(
    const int* __restrict__ gold, const int* __restrict__ lenv,
    const float* __restrict__ em, const float* __restrict__ trans,
    float* __restrict__ out)
{
  __shared__ float trans_s[32][33];
  int tid = threadIdx.x;
  for (int i = tid; i < 1024; i += 64) trans_s[i>>5][i&31] = trans[i];
  __syncthreads();

  int half = tid >> 5;
  int j = tid & 31;                 // tag
  int b = blockIdx.x*2 + half;      // grid 32 -> b 0..63
  int len = lenv[b];
  float score = (j == STOPID) ? 0.f : -10000.f;
  float gscore = 0.f;
  int g_cur = gold[b*T_LEN];

  for (int t = 0; t < len; ++t) {
    float e = em[((size_t)t*64 + b)*32 + j];
    float m = -3.0e38f;
    #pragma unroll
    for (int p = 0; p < 32; ++p) {
      float sp = __shfl(score, p, 32);
      m = fmaxf(m, sp + trans_s[j][p]);
    }
    float se = 0.f;
    #pragma unroll
    for (int p = 0; p < 32; ++p) {
      float sp = __shfl(score, p, 32);
      se += __expf(sp + trans_s[j][p] - m);
    }
    score = e + m + __logf(se);
    if (t + 1 < T_LEN) {
      int g_next = gold[b*T_LEN + t + 1];
      float emg = __shfl(e, g_next, 32);
      gscore += emg + trans_s[g_next][g_cur];
      g_cur = g_next;
    }
  }
  float v = score + trans_s[STOPID][j];
  float m = v;
  #pragma unroll
  for (int off = 16; off; off >>= 1) m = fmaxf(m, __shfl_xor(m, off, 32));
  float se = __expf(v - m);
  #pragma unroll
  for (int off = 16; off; off >>= 1) se += __shfl_xor(se, off, 32);
  float Z = m + __logf(se);
  if (j == 0) {
    int g_last = gold[b*T_LEN + len - 1];
    out[b] = Z - (gscore + trans_s[STOPID][g_last]);
  }
}

extern "C" void kernel_launch(void* const* d_in, const int* in_sizes, int n_in,
                              void* d_out, int out_size, void* d_ws, size_t ws_size,
                              hipStream_t stream)
{
  const int*   inp   = (const int*)  d_in[0];
  const int*   gold  = (const int*)  d_in[1];
  const int*   mask  = (const int*)  d_in[2];
  const float* emb   = (const float*)d_in[3];
  const float* Wih_f = (const float*)d_in[4];
  const float* Whh_f = (const float*)d_in[5];
  const float* b_f   = (const float*)d_in[6];
  const float* Wih_b = (const float*)d_in[7];
  const float* Whh_b = (const float*)d_in[8];
  const float* b_b   = (const float*)d_in[9];
  const float* W_tag = (const float*)d_in[10];
  const float* b_tag = (const float*)d_in[11];
  const float* trans = (const float*)d_in[12];
  float* out = (float*)d_out;

  char* ws = (char*)d_ws;
  u16* whh_bf = (u16*)(ws + 0);                 // 1 MiB
  u16* wih_bf = (u16*)(ws + 1048576);           // 1 MiB
  u16* xW     = (u16*)(ws + 2097152);           // 128 MiB [dir][t][gate][row]   (lifetime: k1..k2)
  float* em   = (float*)(ws + 2097152);         // 8 MiB OVERLAY on xW           (lifetime: k3..k5)
  u16* h_outp = (u16*)(ws + 136314880);         // 32 MiB  [dir][t][row][256]    (lifetime: k2..k3)
  u16* xemb   = (u16*)(ws + 136314880);         // 16 MiB OVERLAY on h_out       (lifetime: kg..k1)
  u16* h_init = (u16*)(ws + 169869312);         // 32 KiB zeros
  u32* cntp   = (u32*)(ws + 169902080);         // 4 KiB barrier flags
  int* lenv   = (int*)(ws + 169906176);         // 256 B

  hipLaunchKernelGGL(k0_cvt,  dim3(1024),     dim3(256), 0, stream,
                     Whh_f, Whh_b, Wih_f, Wih_b, whh_bf, wih_bf);
  hipLaunchKernelGGL(k_init,  dim3(34),       dim3(256), 0, stream,
                     mask, (u32*)h_init, cntp, lenv);
  hipLaunchKernelGGL(kg_emb,  dim3(16384),    dim3(256), 0, stream, inp, emb, xemb);
  hipLaunchKernelGGL(k1_proj, dim3(512, 32),  dim3(256), 0, stream,
                     xemb, wih_bf, b_f, b_b, xW);
  hipLaunchKernelGGL(k2_lstm, dim3(16),       dim3(256), 0, stream,
                     whh_bf, xW, lenv, h_init, h_outp, cntp);
  hipLaunchKernelGGL(k3_emit, dim3(1024),     dim3(256), 0, stream,
                     h_outp, W_tag, b_tag, em);
  hipLaunchKernelGGL(k5_crf,  dim3(32),       dim3(64),  0, stream,
                     gold, lenv, em, trans, out);
}